// Round 10
// baseline (205.894 us; speedup 1.0000x reference)
//
#include <hip/hip_runtime.h>

typedef __bf16 bf16x8 __attribute__((ext_vector_type(8)));
typedef float f32x4 __attribute__((ext_vector_type(4)));
typedef unsigned short u16x8 __attribute__((ext_vector_type(8)));

// ---------- helpers ----------

__device__ __forceinline__ unsigned short f2bf(float f) {
  unsigned u = __builtin_bit_cast(unsigned, f);
  u = (u + 0x7FFFu + ((u >> 16) & 1u)) >> 16;   // RNE
  return (unsigned short)u;
}

__device__ __forceinline__ unsigned cvt_pk_bf16(float lo, float hi) {
  unsigned r;
  asm("v_cvt_pk_bf16_f32 %0, %1, %2" : "=v"(r) : "v"(lo), "v"(hi));
  return r;
}

__device__ __forceinline__ void load_lds16(const void* g, void* l) {
  __builtin_amdgcn_global_load_lds(
      (__attribute__((address_space(1))) void*)g,
      (__attribute__((address_space(3))) void*)l, 16, 0, 0);
}

// ---------- stage 0: dtype convert ----------
__global__ __launch_bounds__(256) void k_convert(
    const float* __restrict__ x,
    const float* __restrict__ wq, const float* __restrict__ wk,
    const float* __restrict__ wv, const float* __restrict__ wo,
    unsigned short* __restrict__ xb,
    unsigned short* __restrict__ wqb, unsigned short* __restrict__ wkb,
    unsigned short* __restrict__ wvb, unsigned short* __restrict__ wob) {
  const int g = blockIdx.x * 256 + threadIdx.x;  // exactly 2M threads
  const float* src;
  unsigned short* dst;
  int off;
  if (g < (1 << 20)) {
    src = x; dst = xb; off = g;
  } else {
    const int q = g - (1 << 20);
    const int t = q >> 18;
    off = q & ((1 << 18) - 1);
    src = (t == 0) ? wq : (t == 1) ? wk : (t == 2) ? wv : wo;
    dst = (t == 0) ? wqb : (t == 1) ? wkb : (t == 2) ? wvb : wob;
  }
  const float4 v = ((const float4*)src)[off];
  ushort4 r;
  r.x = f2bf(v.x); r.y = f2bf(v.y); r.z = f2bf(v.z); r.w = f2bf(v.w);
  ((ushort4*)dst)[off] = r;
}

// ---------- stage 0b: rope table ----------
__global__ __launch_bounds__(256) void k_rope_tab(const int* __restrict__ tpos,
                                                  float* __restrict__ ct,
                                                  float* __restrict__ st) {
  const int idx = blockIdx.x * 256 + threadIdx.x;  // 2048*32 = 64K
  const int s = idx >> 5, i = idx & 31;
  const double p = (double)tpos[s];
  const double f = p * pow(10000.0, -(double)(2 * i) / 64.0);
  ct[idx] = (float)cos(f);
  st[idx] = (float)sin(f);
}

// ---------- GEMM core 128x128, K=1024, BK=32, 3-deep pipeline ----------
__device__ __forceinline__ void gemm_core_1024(
    const unsigned short* __restrict__ Ag,  // at row bm
    const unsigned short* __restrict__ Bg,  // at row bn
    unsigned short* As, unsigned short* Bs, f32x4 (&acc)[4][4], int tid) {
  const int lane = tid & 63;
  const int w = tid >> 6;
  const int wm = (w >> 1) * 64;
  const int wn = (w & 1) * 64;
  const int lr = lane & 15;
  const int lg8 = (lane >> 4) * 8;
  const int c0 = tid, c1 = 256 + tid;
  const int ar0 = c0 >> 2, ac0 = (c0 & 3) * 8;
  const int ar1 = c1 >> 2, ac1 = (c1 & 3) * 8;

  auto stage = [&](int buf, int kt) {
    unsigned short* Ab = As + buf * 4096;
    unsigned short* Bb = Bs + buf * 4096;
    load_lds16(Ag + ar0 * 1024 + kt + ac0, Ab + c0 * 8);
    load_lds16(Ag + ar1 * 1024 + kt + ac1, Ab + c1 * 8);
    load_lds16(Bg + ar0 * 1024 + kt + ac0, Bb + c0 * 8);
    load_lds16(Bg + ar1 * 1024 + kt + ac1, Bb + c1 * 8);
  };

  stage(0, 0);
  stage(1, 32);
  int cur = 0;
  for (int ki = 0; ki < 32; ++ki) {
    if (ki + 2 < 32) {
      int nb = cur + 2; if (nb >= 3) nb -= 3;
      stage(nb, (ki + 2) * 32);
      asm volatile("s_waitcnt vmcnt(8)" ::: "memory");
    } else if (ki + 1 < 32) {
      asm volatile("s_waitcnt vmcnt(4)" ::: "memory");
    } else {
      asm volatile("s_waitcnt vmcnt(0)" ::: "memory");
    }
    __builtin_amdgcn_s_barrier();
    const unsigned short* Ab = As + cur * 4096;
    const unsigned short* Bb = Bs + cur * 4096;
    bf16x8 af[4], bfv[4];
#pragma unroll
    for (int mi = 0; mi < 4; ++mi)
      af[mi] = *(const bf16x8*)(Ab + (wm + mi * 16 + lr) * 32 + lg8);
#pragma unroll
    for (int ni = 0; ni < 4; ++ni)
      bfv[ni] = *(const bf16x8*)(Bb + (wn + ni * 16 + lr) * 32 + lg8);
    __builtin_amdgcn_s_setprio(1);
#pragma unroll
    for (int mi = 0; mi < 4; ++mi)
#pragma unroll
      for (int ni = 0; ni < 4; ++ni)
        acc[mi][ni] = __builtin_amdgcn_mfma_f32_16x16x32_bf16(
            af[mi], bfv[ni], acc[mi][ni], 0, 0, 0);
    __builtin_amdgcn_s_setprio(0);
    __builtin_amdgcn_s_barrier();
    ++cur; if (cur == 3) cur = 0;
  }
}

// ---------- GEMM core 64x128 (BM=64), K=1024, BK=32, 3-deep pipeline ----------
__device__ __forceinline__ void gemm_core_bm64(
    const unsigned short* __restrict__ Ag,  // at row bm (64 rows)
    const unsigned short* __restrict__ Bg,  // at row bn (128 rows)
    unsigned short* As, unsigned short* Bs, f32x4 (&acc)[2][4], int tid) {
  const int lane = tid & 63;
  const int w = tid >> 6;
  const int wm = (w >> 1) * 32;
  const int wn = (w & 1) * 64;
  const int lr = lane & 15;
  const int lg8 = (lane >> 4) * 8;
  const int ar = tid >> 2, ac = (tid & 3) * 8;          // A: 256 chunks, 1/thread
  const int c0 = tid, c1 = 256 + tid;                   // B: 512 chunks, 2/thread
  const int br0 = c0 >> 2, bc0 = (c0 & 3) * 8;
  const int br1 = c1 >> 2, bc1 = (c1 & 3) * 8;

  auto stage = [&](int buf, int kt) {
    load_lds16(Ag + ar * 1024 + kt + ac, As + buf * 2048 + tid * 8);
    load_lds16(Bg + br0 * 1024 + kt + bc0, Bs + buf * 4096 + c0 * 8);
    load_lds16(Bg + br1 * 1024 + kt + bc1, Bs + buf * 4096 + c1 * 8);
  };

  stage(0, 0);
  stage(1, 32);
  int cur = 0;
  for (int ki = 0; ki < 32; ++ki) {
    if (ki + 2 < 32) {
      int nb = cur + 2; if (nb >= 3) nb -= 3;
      stage(nb, (ki + 2) * 32);
      asm volatile("s_waitcnt vmcnt(6)" ::: "memory");
    } else if (ki + 1 < 32) {
      asm volatile("s_waitcnt vmcnt(3)" ::: "memory");
    } else {
      asm volatile("s_waitcnt vmcnt(0)" ::: "memory");
    }
    __builtin_amdgcn_s_barrier();
    const unsigned short* Ab = As + cur * 2048;
    const unsigned short* Bb = Bs + cur * 4096;
    bf16x8 af[2], bfv[4];
#pragma unroll
    for (int mi = 0; mi < 2; ++mi)
      af[mi] = *(const bf16x8*)(Ab + (wm + mi * 16 + lr) * 32 + lg8);
#pragma unroll
    for (int ni = 0; ni < 4; ++ni)
      bfv[ni] = *(const bf16x8*)(Bb + (wn + ni * 16 + lr) * 32 + lg8);
    __builtin_amdgcn_s_setprio(1);
#pragma unroll
    for (int mi = 0; mi < 2; ++mi)
#pragma unroll
      for (int ni = 0; ni < 4; ++ni)
        acc[mi][ni] = __builtin_amdgcn_mfma_f32_16x16x32_bf16(
            af[mi], bfv[ni], acc[mi][ni], 0, 0, 0);
    __builtin_amdgcn_s_setprio(0);
    __builtin_amdgcn_s_barrier();
    ++cur; if (cur == 3) cur = 0;
  }
}

// ---------- stage 1: q/k/v projection + rope ----------
// Q,K out: bf16 [B*H][S][64]. V out: TRANSPOSED bf16 [B*H][64][S].
__global__ __launch_bounds__(256) void k_proj(
    const unsigned short* __restrict__ Xb,
    const unsigned short* __restrict__ Wq, const unsigned short* __restrict__ Wk,
    const unsigned short* __restrict__ Wv,
    const float* __restrict__ ctab, const float* __restrict__ stab,
    unsigned short* __restrict__ Qo, unsigned short* __restrict__ Ko,
    unsigned short* __restrict__ Vo) {
  __shared__ __align__(16) unsigned short As[3 * 128 * 32];
  __shared__ __align__(16) unsigned short Bs[3 * 128 * 32];
  const int z = blockIdx.z;
  const unsigned short* Wsel = (z == 0) ? Wq : (z == 1) ? Wk : Wv;
  unsigned short* Out = (z == 0) ? Qo : (z == 1) ? Ko : Vo;
  const int tid = threadIdx.x;
  const int bm = blockIdx.x * 128, bn = blockIdx.y * 128;
  f32x4 acc[4][4] = {};
  gemm_core_1024(Xb + (size_t)bm * 1024, Wsel + (size_t)bn * 1024, As, Bs, acc, tid);

  const int lane = tid & 63, w = tid >> 6;
  const int wm = (w >> 1) * 64, wn = (w & 1) * 64;
  const int lr = lane & 15, lg = lane >> 4;

  if (z == 2) {
    // V: pack 4 consecutive s (reg dim) -> one 8B store into [bh][d][s]
#pragma unroll
    for (int mi = 0; mi < 4; ++mi) {
      const int r0 = bm + wm + mi * 16 + lg * 4;  // rows r0..r0+3, same b
      const int s = r0 & 2047, b = r0 >> 11;
#pragma unroll
      for (int ni = 0; ni < 4; ++ni) {
        const int e = bn + wn + ni * 16 + lr;
        const int h = e >> 6, d = e & 63;
        ushort4 pk;
        pk.x = f2bf(acc[mi][ni][0]);
        pk.y = f2bf(acc[mi][ni][1]);
        pk.z = f2bf(acc[mi][ni][2]);
        pk.w = f2bf(acc[mi][ni][3]);
        *(ushort4*)&Out[((size_t)(b * 16 + h) * 64 + d) * 2048 + s] = pk;
      }
    }
    return;
  }

  const bool odd = lane & 1;
#pragma unroll
  for (int mi = 0; mi < 4; ++mi) {
#pragma unroll
    for (int ni = 0; ni < 4; ++ni) {
#pragma unroll
      for (int reg = 0; reg < 4; ++reg) {
        const int r = bm + wm + mi * 16 + lg * 4 + reg;  // D row -> (b,s)
        const int e = bn + wn + ni * 16 + lr;            // D col -> (h,d)
        float val = acc[mi][ni][reg];
        const float partner = __shfl_xor(val, 1);
        const int s = r & 2047, b = r >> 11;
        const int h = e >> 6, d = e & 63;
        const int i = d >> 1;
        const float c = ctab[s * 32 + i];
        const float sn = stab[s * 32 + i];
        const float outv = odd ? (val * c + partner * sn) : (val * c - partner * sn);
        Out[((size_t)(b * 16 + h) * 2048 + s) * 64 + d] = f2bf(outv);
      }
    }
  }
}

// ---------- stage 2: causal flash attention, all-register KV, paired strips ----------
// 2048 blocks of 64 threads. Block L: bh=(L&7)*4+((L>>3)&3) (XCD-clustered),
// p=L>>5. Wave owns strips A=p, B=127-p over one shared KV stream. Swapped MFMA:
// S=mfma(K,Q) -> lane-local softmax (q=lane&15); l via ones-A-frag MFMA (no
// shuffles); PV=mfma(V^T,P) with V^T straight from global into regs (dbuf, no
// LDS, no manual waitcnt). Two P buffers so strip chains overlap. No barriers.
__global__ __launch_bounds__(64, 2) void k_attn(
    const unsigned short* __restrict__ Q, const unsigned short* __restrict__ K,
    const unsigned short* __restrict__ Vt, unsigned short* __restrict__ O) {
  __shared__ __align__(16) unsigned short PlB[16 * 68];
  __shared__ __align__(16) unsigned short PlA[16 * 68];
  const int L = blockIdx.x;
  const int bh = (L & 7) * 4 + ((L >> 3) & 3);
  const int p = L >> 5;                 // 0..63
  const int qrowA = p * 16, qrowB = (127 - p) * 16;
  const int Ta = (qrowA + 79) >> 6;
  const int Tb = (qrowB + 79) >> 6;     // >= Ta; loop count
  const int lane = threadIdx.x & 63;
  const int lr = lane & 15, lg = lane >> 4;
  const unsigned short* Qg = Q + (size_t)bh * 2048 * 64;
  const unsigned short* Kg = K + (size_t)bh * 2048 * 64;
  const unsigned short* Vg = Vt + (size_t)bh * 64 * 2048;

  // Q fragments (B-operand rows = q = lane&15)
  bf16x8 qfA[2], qfB[2];
#pragma unroll
  for (int h = 0; h < 2; ++h) {
    qfA[h] = *(const bf16x8*)(Qg + (qrowA + lr) * 64 + h * 32 + lg * 8);
    qfB[h] = *(const bf16x8*)(Qg + (qrowB + lr) * 64 + h * 32 + lg * 8);
  }

  // ones A-fragment (row-sum via MFMA: D[m][q] = sum_k P[k][q] for every m)
  u16x8 ouv;
#pragma unroll
  for (int j = 0; j < 8; ++j) ouv[j] = 0x3F80;  // bf16 1.0
  const bf16x8 onesf = __builtin_bit_cast(bf16x8, ouv);

  f32x4 oA[4] = {}, oB[4] = {};            // O^T: d = nt*16+lg*4+reg, q = lr
  f32x4 lAa = {}, lBa = {};                // row-sum accs (all 4 regs equal)
  float mA = -__builtin_inff(), mB = -__builtin_inff();

  const float SCL = 0.125f * 1.44269504088896f;  // 1/sqrt(64) * log2(e)

  const int kbase = lr * 64 + lg * 8;
  const int vbase = lr * 2048 + lg * 8;

  auto loadK = [&](bf16x8 (&kd)[4][2], int kv) {
    const unsigned short* base = Kg + (size_t)kv * 4096 + kbase;
#pragma unroll
    for (int nt = 0; nt < 4; ++nt)
#pragma unroll
      for (int h = 0; h < 2; ++h)
        kd[nt][h] = *(const bf16x8*)(base + nt * 1024 + h * 32);
  };
  auto loadV = [&](bf16x8 (&vd)[4][2], int kv) {
    const unsigned short* base = Vg + vbase + kv * 64;
#pragma unroll
    for (int nt = 0; nt < 4; ++nt)
#pragma unroll
      for (int ks = 0; ks < 2; ++ks)
        vd[nt][ks] = *(const bf16x8*)(base + nt * 16 * 2048 + ks * 32);
  };

  // softmax for one strip: mask, local max tree (shuffles issued by caller
  // pattern interleave via inlining), rescale, exp2+pack into its P buffer.
  auto soft = [&](f32x4 (&s)[4], float& m, f32x4& la, f32x4 (&oacc)[4],
                  int qrow, bool needmask, int kv, unsigned short* Pl) {
    if (needmask) {
      const int qg = qrow + lr;
#pragma unroll
      for (int nt = 0; nt < 4; ++nt)
#pragma unroll
        for (int reg = 0; reg < 4; ++reg) {
          const int kg = kv * 64 + nt * 16 + lg * 4 + reg;
          if (kg > qg) s[nt][reg] = -__builtin_inff();
        }
    }
    float t0 = fmaxf(fmaxf(s[0][0], s[0][1]), fmaxf(s[0][2], s[0][3]));
    float t1 = fmaxf(fmaxf(s[1][0], s[1][1]), fmaxf(s[1][2], s[1][3]));
    float t2 = fmaxf(fmaxf(s[2][0], s[2][1]), fmaxf(s[2][2], s[2][3]));
    float t3 = fmaxf(fmaxf(s[3][0], s[3][1]), fmaxf(s[3][2], s[3][3]));
    float pm = fmaxf(fmaxf(t0, t1), fmaxf(t2, t3));
    pm = fmaxf(pm, __shfl_xor(pm, 16));
    pm = fmaxf(pm, __shfl_xor(pm, 32));
    if (__any(pm > m)) {  // deferred rescale
      const float mn = fmaxf(m, pm);
      const float al = exp2f(SCL * (m - mn));
      m = mn;
#pragma unroll
      for (int reg = 0; reg < 4; ++reg) la[reg] *= al;
#pragma unroll
      for (int nt = 0; nt < 4; ++nt)
#pragma unroll
        for (int reg = 0; reg < 4; ++reg) oacc[nt][reg] *= al;
    }
    const float msc = SCL * m;
    unsigned short* prow = Pl + lr * 68;
#pragma unroll
    for (int nt = 0; nt < 4; ++nt) {
      const float p0 = exp2f(s[nt][0] * SCL - msc);
      const float p1 = exp2f(s[nt][1] * SCL - msc);
      const float p2 = exp2f(s[nt][2] * SCL - msc);
      const float p3 = exp2f(s[nt][3] * SCL - msc);
      const unsigned w01 = cvt_pk_bf16(p0, p1);
      const unsigned w23 = cvt_pk_bf16(p2, p3);
      ushort4 pk;
      pk.x = (unsigned short)w01; pk.y = (unsigned short)(w01 >> 16);
      pk.z = (unsigned short)w23; pk.w = (unsigned short)(w23 >> 16);
      *(ushort4*)(prow + nt * 16 + lg * 4) = pk;
    }
  };

  bf16x8 kbufA[4][2], kbufB[4][2], vbufA[4][2], vbufB[4][2];
  loadK(kbufA, 0);
  loadV(vbufA, 0);

  auto iter = [&](int t, bf16x8 (&kc)[4][2], bf16x8 (&kn)[4][2],
                  bf16x8 (&vc)[4][2], bf16x8 (&vn)[4][2]) {
    const bool more = (t + 1 < Tb);
    const bool actA = (t < Ta);
    if (more) { loadK(kn, t + 1); loadV(vn, t + 1); }

    // ---- S = K·Q^T (swapped): lane holds S[k][q=lr] ----
    f32x4 sB[4], sA[4];
    __builtin_amdgcn_s_setprio(1);
#pragma unroll
    for (int nt = 0; nt < 4; ++nt) {
      f32x4 z = {0.f, 0.f, 0.f, 0.f};
      z = __builtin_amdgcn_mfma_f32_16x16x32_bf16(kc[nt][0], qfB[0], z, 0, 0, 0);
      sB[nt] = __builtin_amdgcn_mfma_f32_16x16x32_bf16(kc[nt][1], qfB[1], z, 0, 0, 0);
    }
    if (actA)
#pragma unroll
      for (int nt = 0; nt < 4; ++nt) {
        f32x4 z = {0.f, 0.f, 0.f, 0.f};
        z = __builtin_amdgcn_mfma_f32_16x16x32_bf16(kc[nt][0], qfA[0], z, 0, 0, 0);
        sA[nt] = __builtin_amdgcn_mfma_f32_16x16x32_bf16(kc[nt][1], qfA[1], z, 0, 0, 0);
      }
    __builtin_amdgcn_s_setprio(0);

    // ---- softmax (both strips in one region so chains interleave) ----
    bf16x8 paB[2], paA[2];
    if (actA) {
      soft(sB, mB, lBa, oB, qrowB, t == Tb - 1, t, PlB);
      soft(sA, mA, lAa, oA, qrowA, t == Ta - 1, t, PlA);
#pragma unroll
      for (int ks = 0; ks < 2; ++ks) {
        paB[ks] = *(const bf16x8*)(PlB + lr * 68 + ks * 32 + lg * 8);
        paA[ks] = *(const bf16x8*)(PlA + lr * 68 + ks * 32 + lg * 8);
      }
    } else {
      soft(sB, mB, lBa, oB, qrowB, t == Tb - 1, t, PlB);
#pragma unroll
      for (int ks = 0; ks < 2; ++ks)
        paB[ks] = *(const bf16x8*)(PlB + lr * 68 + ks * 32 + lg * 8);
    }

    // ---- l += ones·P ; O^T += V^T·P ----
    __builtin_amdgcn_s_setprio(1);
    lBa = __builtin_amdgcn_mfma_f32_16x16x32_bf16(onesf, paB[0], lBa, 0, 0, 0);
    lBa = __builtin_amdgcn_mfma_f32_16x16x32_bf16(onesf, paB[1], lBa, 0, 0, 0);
    if (actA) {
      lAa = __builtin_amdgcn_mfma_f32_16x16x32_bf16(onesf, paA[0], lAa, 0, 0, 0);
      lAa = __builtin_amdgcn_mfma_f32_16x16x32_bf16(onesf, paA[1], lAa, 0, 0, 0);
    }
#pragma unroll
    for (int nt = 0; nt < 4; ++nt) {
      oB[nt] = __builtin_amdgcn_mfma_f32_16x16x32_bf16(vc[nt][0], paB[0], oB[nt], 0, 0, 0);
      oB[nt] = __builtin_amdgcn_mfma_f32_16x16x32_bf16(vc[nt][1], paB[1], oB[nt], 0, 0, 0);
      if (actA) {
        oA[nt] = __builtin_amdgcn_mfma_f32_16x16x32_bf16(vc[nt][0], paA[0], oA[nt], 0, 0, 0);
        oA[nt] = __builtin_amdgcn_mfma_f32_16x16x32_bf16(vc[nt][1], paA[1], oA[nt], 0, 0, 0);
      }
    }
    __builtin_amdgcn_s_setprio(0);
  };

  int t = 0;
  for (;;) {
    iter(t, kbufA, kbufB, vbufA, vbufB); ++t; if (t >= Tb) break;
    iter(t, kbufB, kbufA, vbufB, vbufA); ++t; if (t >= Tb) break;
  }

  // ---- normalize + write O^T as bf16 [B][S][H*64]: 4 packed 8B stores/strip ----
  const int b = bh >> 4, h = bh & 15;
  auto wrO = [&](f32x4 (&oacc)[4], float l, int qrow) {
    const float inv = 1.0f / l;
    unsigned short* dst = &O[((size_t)b * 2048 + qrow + lr) * 1024 + h * 64];
#pragma unroll
    for (int nt = 0; nt < 4; ++nt) {
      const unsigned w01 = cvt_pk_bf16(oacc[nt][0] * inv, oacc[nt][1] * inv);
      const unsigned w23 = cvt_pk_bf16(oacc[nt][2] * inv, oacc[nt][3] * inv);
      ushort4 pk;
      pk.x = (unsigned short)w01; pk.y = (unsigned short)(w01 >> 16);
      pk.z = (unsigned short)w23; pk.w = (unsigned short)(w23 >> 16);
      *(ushort4*)(dst + nt * 16 + lg * 4) = pk;
    }
  };
  wrO(oA, lAa[0], qrowA);
  wrO(oB, lBa[0], qrowB);
}

// ---------- stage 3: output projection (BM=64 tiles, 2 blocks/CU), f32 out ----------
__global__ __launch_bounds__(256) void k_out(const unsigned short* __restrict__ Ab,
                                             const unsigned short* __restrict__ Wo,
                                             float* __restrict__ Out) {
  __shared__ __align__(16) unsigned short As[3 * 64 * 32];
  __shared__ __align__(16) unsigned short Bs[3 * 128 * 32];
  const int tid = threadIdx.x;
  const int bm = blockIdx.x * 64, bn = blockIdx.y * 128;
  f32x4 acc[2][4] = {};
  gemm_core_bm64(Ab + (size_t)bm * 1024, Wo + (size_t)bn * 1024, As, Bs, acc, tid);
  const int lane = tid & 63, w = tid >> 6;
  const int wm = (w >> 1) * 32, wn = (w & 1) * 64;
  const int lr = lane & 15, lg = lane >> 4;
#pragma unroll
  for (int mi = 0; mi < 2; ++mi)
#pragma unroll
    for (int ni = 0; ni < 4; ++ni)
#pragma unroll
      for (int reg = 0; reg < 4; ++reg) {
        const int r = bm + wm + mi * 16 + lg * 4 + reg;
        const int e = bn + wn + ni * 16 + lr;
        Out[(size_t)r * 1024 + e] = acc[mi][ni][reg];
      }
}

// ---------- launch ----------
extern "C" void kernel_launch(void* const* d_in, const int* in_sizes, int n_in,
                              void* d_out, int out_size, void* d_ws, size_t ws_size,
                              hipStream_t stream) {
  const float* x = (const float*)d_in[0];
  const float* Wq = (const float*)d_in[1];
  const float* Wk = (const float*)d_in[2];
  const float* Wv = (const float*)d_in[3];
  const float* Wo = (const float*)d_in[4];
  const int* tpos = (const int*)d_in[5];
  float* out = (float*)d_out;
  char* ws = (char*)d_ws;
  const size_t MB = 1024 * 1024;
  unsigned short* xb = (unsigned short*)(ws);             // 8 MB
  unsigned short* wqb = (unsigned short*)(ws + 8 * MB);   // 2 MB
  unsigned short* wkb = (unsigned short*)(ws + 10 * MB);
  unsigned short* wvb = (unsigned short*)(ws + 12 * MB);
  unsigned short* wob = (unsigned short*)(ws + 14 * MB);
  unsigned short* Qb = (unsigned short*)(ws + 16 * MB);   // 8 MB each
  unsigned short* Kb = (unsigned short*)(ws + 24 * MB);
  unsigned short* Vtb = (unsigned short*)(ws + 32 * MB);  // transposed V
  unsigned short* Ab = (unsigned short*)(ws + 40 * MB);
  float* ctab = (float*)(ws + 48 * MB);                   // 256 KB
  float* stab = (float*)(ws + 48 * MB + 256 * 1024);

  k_convert<<<dim3(8192), dim3(256), 0, stream>>>(x, Wq, Wk, Wv, Wo, xb, wqb, wkb,
                                                  wvb, wob);
  k_rope_tab<<<dim3(256), dim3(256), 0, stream>>>(tpos, ctab, stab);
  k_proj<<<dim3(32, 8, 3), dim3(256), 0, stream>>>(xb, wqb, wkb, wvb, ctab, stab,
                                                   Qb, Kb, Vtb);
  k_attn<<<dim3(2048), dim3(64), 0, stream>>>(Qb, Kb, Vtb, Ab);
  k_out<<<dim3(64, 8), dim3(256), 0, stream>>>(Ab, wob, out);
}

// Round 11
// 151.276 us; speedup vs baseline: 1.3610x; 1.3610x over previous
//
#include <hip/hip_runtime.h>

typedef __bf16 bf16x8 __attribute__((ext_vector_type(8)));
typedef float f32x4 __attribute__((ext_vector_type(4)));
typedef unsigned short u16x8 __attribute__((ext_vector_type(8)));

// ---------- helpers ----------

__device__ __forceinline__ unsigned short f2bf(float f) {
  unsigned u = __builtin_bit_cast(unsigned, f);
  u = (u + 0x7FFFu + ((u >> 16) & 1u)) >> 16;   // RNE
  return (unsigned short)u;
}

__device__ __forceinline__ unsigned cvt_pk_bf16(float lo, float hi) {
  unsigned r;
  asm("v_cvt_pk_bf16_f32 %0, %1, %2" : "=v"(r) : "v"(lo), "v"(hi));
  return r;
}

__device__ __forceinline__ void load_lds16(const void* g, void* l) {
  __builtin_amdgcn_global_load_lds(
      (__attribute__((address_space(1))) void*)g,
      (__attribute__((address_space(3))) void*)l, 16, 0, 0);
}

// ---------- stage 0: dtype convert ----------
__global__ __launch_bounds__(256) void k_convert(
    const float* __restrict__ x,
    const float* __restrict__ wq, const float* __restrict__ wk,
    const float* __restrict__ wv, const float* __restrict__ wo,
    unsigned short* __restrict__ xb,
    unsigned short* __restrict__ wqb, unsigned short* __restrict__ wkb,
    unsigned short* __restrict__ wvb, unsigned short* __restrict__ wob) {
  const int g = blockIdx.x * 256 + threadIdx.x;  // exactly 2M threads
  const float* src;
  unsigned short* dst;
  int off;
  if (g < (1 << 20)) {
    src = x; dst = xb; off = g;
  } else {
    const int q = g - (1 << 20);
    const int t = q >> 18;
    off = q & ((1 << 18) - 1);
    src = (t == 0) ? wq : (t == 1) ? wk : (t == 2) ? wv : wo;
    dst = (t == 0) ? wqb : (t == 1) ? wkb : (t == 2) ? wvb : wob;
  }
  const float4 v = ((const float4*)src)[off];
  ushort4 r;
  r.x = f2bf(v.x); r.y = f2bf(v.y); r.z = f2bf(v.z); r.w = f2bf(v.w);
  ((ushort4*)dst)[off] = r;
}

// ---------- stage 0b: rope table ----------
__global__ __launch_bounds__(256) void k_rope_tab(const int* __restrict__ tpos,
                                                  float* __restrict__ ct,
                                                  float* __restrict__ st) {
  const int idx = blockIdx.x * 256 + threadIdx.x;  // 2048*32 = 64K
  const int s = idx >> 5, i = idx & 31;
  const double p = (double)tpos[s];
  const double f = p * pow(10000.0, -(double)(2 * i) / 64.0);
  ct[idx] = (float)cos(f);
  st[idx] = (float)sin(f);
}

// ---------- GEMM core 128x128, K=1024, BK=32, 3-deep pipeline ----------
__device__ __forceinline__ void gemm_core_1024(
    const unsigned short* __restrict__ Ag,  // at row bm
    const unsigned short* __restrict__ Bg,  // at row bn
    unsigned short* As, unsigned short* Bs, f32x4 (&acc)[4][4], int tid) {
  const int lane = tid & 63;
  const int w = tid >> 6;
  const int wm = (w >> 1) * 64;
  const int wn = (w & 1) * 64;
  const int lr = lane & 15;
  const int lg8 = (lane >> 4) * 8;
  const int c0 = tid, c1 = 256 + tid;
  const int ar0 = c0 >> 2, ac0 = (c0 & 3) * 8;
  const int ar1 = c1 >> 2, ac1 = (c1 & 3) * 8;

  auto stage = [&](int buf, int kt) {
    unsigned short* Ab = As + buf * 4096;
    unsigned short* Bb = Bs + buf * 4096;
    load_lds16(Ag + ar0 * 1024 + kt + ac0, Ab + c0 * 8);
    load_lds16(Ag + ar1 * 1024 + kt + ac1, Ab + c1 * 8);
    load_lds16(Bg + ar0 * 1024 + kt + ac0, Bb + c0 * 8);
    load_lds16(Bg + ar1 * 1024 + kt + ac1, Bb + c1 * 8);
  };

  stage(0, 0);
  stage(1, 32);
  int cur = 0;
  for (int ki = 0; ki < 32; ++ki) {
    if (ki + 2 < 32) {
      int nb = cur + 2; if (nb >= 3) nb -= 3;
      stage(nb, (ki + 2) * 32);
      asm volatile("s_waitcnt vmcnt(8)" ::: "memory");
    } else if (ki + 1 < 32) {
      asm volatile("s_waitcnt vmcnt(4)" ::: "memory");
    } else {
      asm volatile("s_waitcnt vmcnt(0)" ::: "memory");
    }
    __builtin_amdgcn_s_barrier();
    const unsigned short* Ab = As + cur * 4096;
    const unsigned short* Bb = Bs + cur * 4096;
    bf16x8 af[4], bfv[4];
#pragma unroll
    for (int mi = 0; mi < 4; ++mi)
      af[mi] = *(const bf16x8*)(Ab + (wm + mi * 16 + lr) * 32 + lg8);
#pragma unroll
    for (int ni = 0; ni < 4; ++ni)
      bfv[ni] = *(const bf16x8*)(Bb + (wn + ni * 16 + lr) * 32 + lg8);
    __builtin_amdgcn_s_setprio(1);
#pragma unroll
    for (int mi = 0; mi < 4; ++mi)
#pragma unroll
      for (int ni = 0; ni < 4; ++ni)
        acc[mi][ni] = __builtin_amdgcn_mfma_f32_16x16x32_bf16(
            af[mi], bfv[ni], acc[mi][ni], 0, 0, 0);
    __builtin_amdgcn_s_setprio(0);
    __builtin_amdgcn_s_barrier();
    ++cur; if (cur == 3) cur = 0;
  }
}

// ---------- GEMM core 64x128 (BM=64), K=1024, BK=32, 3-deep pipeline ----------
__device__ __forceinline__ void gemm_core_bm64(
    const unsigned short* __restrict__ Ag,  // at row bm (64 rows)
    const unsigned short* __restrict__ Bg,  // at row bn (128 rows)
    unsigned short* As, unsigned short* Bs, f32x4 (&acc)[2][4], int tid) {
  const int lane = tid & 63;
  const int w = tid >> 6;
  const int wm = (w >> 1) * 32;
  const int wn = (w & 1) * 64;
  const int lr = lane & 15;
  const int lg8 = (lane >> 4) * 8;
  const int ar = tid >> 2, ac = (tid & 3) * 8;          // A: 256 chunks, 1/thread
  const int c0 = tid, c1 = 256 + tid;                   // B: 512 chunks, 2/thread
  const int br0 = c0 >> 2, bc0 = (c0 & 3) * 8;
  const int br1 = c1 >> 2, bc1 = (c1 & 3) * 8;

  auto stage = [&](int buf, int kt) {
    load_lds16(Ag + ar * 1024 + kt + ac, As + buf * 2048 + tid * 8);
    load_lds16(Bg + br0 * 1024 + kt + bc0, Bs + buf * 4096 + c0 * 8);
    load_lds16(Bg + br1 * 1024 + kt + bc1, Bs + buf * 4096 + c1 * 8);
  };

  stage(0, 0);
  stage(1, 32);
  int cur = 0;
  for (int ki = 0; ki < 32; ++ki) {
    if (ki + 2 < 32) {
      int nb = cur + 2; if (nb >= 3) nb -= 3;
      stage(nb, (ki + 2) * 32);
      asm volatile("s_waitcnt vmcnt(6)" ::: "memory");
    } else if (ki + 1 < 32) {
      asm volatile("s_waitcnt vmcnt(3)" ::: "memory");
    } else {
      asm volatile("s_waitcnt vmcnt(0)" ::: "memory");
    }
    __builtin_amdgcn_s_barrier();
    const unsigned short* Ab = As + cur * 2048;
    const unsigned short* Bb = Bs + cur * 4096;
    bf16x8 af[2], bfv[4];
#pragma unroll
    for (int mi = 0; mi < 2; ++mi)
      af[mi] = *(const bf16x8*)(Ab + (wm + mi * 16 + lr) * 32 + lg8);
#pragma unroll
    for (int ni = 0; ni < 4; ++ni)
      bfv[ni] = *(const bf16x8*)(Bb + (wn + ni * 16 + lr) * 32 + lg8);
    __builtin_amdgcn_s_setprio(1);
#pragma unroll
    for (int mi = 0; mi < 2; ++mi)
#pragma unroll
      for (int ni = 0; ni < 4; ++ni)
        acc[mi][ni] = __builtin_amdgcn_mfma_f32_16x16x32_bf16(
            af[mi], bfv[ni], acc[mi][ni], 0, 0, 0);
    __builtin_amdgcn_s_setprio(0);
    __builtin_amdgcn_s_barrier();
    ++cur; if (cur == 3) cur = 0;
  }
}

// ---------- stage 1: q/k/v projection + rope ----------
// Q,K out: bf16 [B*H][S][64]. V out: TRANSPOSED bf16 [B*H][64][S].
__global__ __launch_bounds__(256) void k_proj(
    const unsigned short* __restrict__ Xb,
    const unsigned short* __restrict__ Wq, const unsigned short* __restrict__ Wk,
    const unsigned short* __restrict__ Wv,
    const float* __restrict__ ctab, const float* __restrict__ stab,
    unsigned short* __restrict__ Qo, unsigned short* __restrict__ Ko,
    unsigned short* __restrict__ Vo) {
  __shared__ __align__(16) unsigned short As[3 * 128 * 32];
  __shared__ __align__(16) unsigned short Bs[3 * 128 * 32];
  const int z = blockIdx.z;
  const unsigned short* Wsel = (z == 0) ? Wq : (z == 1) ? Wk : Wv;
  unsigned short* Out = (z == 0) ? Qo : (z == 1) ? Ko : Vo;
  const int tid = threadIdx.x;
  const int bm = blockIdx.x * 128, bn = blockIdx.y * 128;
  f32x4 acc[4][4] = {};
  gemm_core_1024(Xb + (size_t)bm * 1024, Wsel + (size_t)bn * 1024, As, Bs, acc, tid);

  const int lane = tid & 63, w = tid >> 6;
  const int wm = (w >> 1) * 64, wn = (w & 1) * 64;
  const int lr = lane & 15, lg = lane >> 4;

  if (z == 2) {
    // V: pack 4 consecutive s (reg dim) -> one 8B store into [bh][d][s]
#pragma unroll
    for (int mi = 0; mi < 4; ++mi) {
      const int r0 = bm + wm + mi * 16 + lg * 4;  // rows r0..r0+3, same b
      const int s = r0 & 2047, b = r0 >> 11;
#pragma unroll
      for (int ni = 0; ni < 4; ++ni) {
        const int e = bn + wn + ni * 16 + lr;
        const int h = e >> 6, d = e & 63;
        ushort4 pk;
        pk.x = f2bf(acc[mi][ni][0]);
        pk.y = f2bf(acc[mi][ni][1]);
        pk.z = f2bf(acc[mi][ni][2]);
        pk.w = f2bf(acc[mi][ni][3]);
        *(ushort4*)&Out[((size_t)(b * 16 + h) * 64 + d) * 2048 + s] = pk;
      }
    }
    return;
  }

  const bool odd = lane & 1;
#pragma unroll
  for (int mi = 0; mi < 4; ++mi) {
#pragma unroll
    for (int ni = 0; ni < 4; ++ni) {
#pragma unroll
      for (int reg = 0; reg < 4; ++reg) {
        const int r = bm + wm + mi * 16 + lg * 4 + reg;  // D row -> (b,s)
        const int e = bn + wn + ni * 16 + lr;            // D col -> (h,d)
        float val = acc[mi][ni][reg];
        const float partner = __shfl_xor(val, 1);
        const int s = r & 2047, b = r >> 11;
        const int h = e >> 6, d = e & 63;
        const int i = d >> 1;
        const float c = ctab[s * 32 + i];
        const float sn = stab[s * 32 + i];
        const float outv = odd ? (val * c + partner * sn) : (val * c - partner * sn);
        Out[((size_t)(b * 16 + h) * 2048 + s) * 64 + d] = f2bf(outv);
      }
    }
  }
}

// ---------- stage 2: causal flash attention, concurrent paired strips ----------
// 2048 blocks of 64 threads. Block L: bh=(L&7)*4+((L>>3)&3) (XCD-clustered),
// p=L>>5. Wave owns strips A=p, B=127-p over one shared KV stream. Swapped MFMA:
// S=mfma(K,Q) -> lane-local softmax (q=lane&15). Row-sum l via ones-A-frag MFMA
// (no shuffles). K reg dbuf, V LDS-DMA dbuf with counted vmcnt. No barriers.
__global__ __launch_bounds__(64, 2) void k_attn(
    const unsigned short* __restrict__ Q, const unsigned short* __restrict__ K,
    const unsigned short* __restrict__ Vt, unsigned short* __restrict__ O) {
  __shared__ __align__(16) unsigned short Vs[2][64 * 64];  // swizzled [dv][kv]
  __shared__ __align__(16) unsigned short Pl[16 * 68];     // P[q][k], shared B->A
  const int L = blockIdx.x;
  const int bh = (L & 7) * 4 + ((L >> 3) & 3);
  const int p = L >> 5;                 // 0..63
  const int qrowA = p * 16, qrowB = (127 - p) * 16;
  const int Ta = (qrowA + 79) >> 6;
  const int Tb = (qrowB + 79) >> 6;     // >= Ta; loop count
  const int lane = threadIdx.x & 63;
  const int lr = lane & 15, lg = lane >> 4;
  const unsigned short* Qg = Q + (size_t)bh * 2048 * 64;
  const unsigned short* Kg = K + (size_t)bh * 2048 * 64;
  const unsigned short* Vg = Vt + (size_t)bh * 64 * 2048;

  // Q fragments (B-operand rows = q = lane&15)
  bf16x8 qfA[2], qfB[2];
#pragma unroll
  for (int h = 0; h < 2; ++h) {
    qfA[h] = *(const bf16x8*)(Qg + (qrowA + lr) * 64 + h * 32 + lg * 8);
    qfB[h] = *(const bf16x8*)(Qg + (qrowB + lr) * 64 + h * 32 + lg * 8);
  }

  // ones A-fragment (row-sum via MFMA: D[m][q] = sum_k P[k][q] for every m)
  u16x8 ouv;
#pragma unroll
  for (int j = 0; j < 8; ++j) ouv[j] = 0x3F80;  // bf16 1.0
  const bf16x8 onesf = __builtin_bit_cast(bf16x8, ouv);

  f32x4 oA[4] = {}, oB[4] = {};            // O^T: d = nt*16+lg*4+reg, q = lr
  f32x4 lAa = {}, lBa = {};                // row-sum accs (all regs equal)
  float mA = -__builtin_inff(), mB = -__builtin_inff();

  const float SCL = 0.125f * 1.44269504088896f;  // 1/sqrt(64) * log2(e)

  const int kbase = lr * 64 + lg * 8;
  const int vbase = (lane >> 3) * 2048 + (((lane & 7) ^ (lane >> 3)) * 8);

  auto loadK = [&](bf16x8 (&kd)[4][2], int kv) {
    const unsigned short* base = Kg + (size_t)kv * 4096 + kbase;
#pragma unroll
    for (int nt = 0; nt < 4; ++nt)
#pragma unroll
      for (int h = 0; h < 2; ++h)
        kd[nt][h] = *(const bf16x8*)(base + nt * 1024 + h * 32);
  };
  auto issueV = [&](int buf, int kv) {
    const unsigned short* src = Vg + kv * 64 + vbase;
    unsigned short* dst = &Vs[buf][0] + lane * 8;
#pragma unroll
    for (int i0 = 0; i0 < 8; ++i0)
      load_lds16(src + i0 * 16384, dst + i0 * 512);
  };

  // lane-local softmax for one strip: mask, max tree + 2 shuffles, deferred
  // rescale, exp2 + cvt_pk packed P store. Row-sum handled later by ones-MFMA.
  auto soft = [&](f32x4 (&s)[4], float& m, f32x4& la, f32x4 (&oacc)[4],
                  int qrow, bool needmask, int kv) {
    if (needmask) {
      const int qg = qrow + lr;
#pragma unroll
      for (int nt = 0; nt < 4; ++nt)
#pragma unroll
        for (int reg = 0; reg < 4; ++reg) {
          const int kg = kv * 64 + nt * 16 + lg * 4 + reg;
          if (kg > qg) s[nt][reg] = -__builtin_inff();
        }
    }
    float t0 = fmaxf(fmaxf(s[0][0], s[0][1]), fmaxf(s[0][2], s[0][3]));
    float t1 = fmaxf(fmaxf(s[1][0], s[1][1]), fmaxf(s[1][2], s[1][3]));
    float t2 = fmaxf(fmaxf(s[2][0], s[2][1]), fmaxf(s[2][2], s[2][3]));
    float t3 = fmaxf(fmaxf(s[3][0], s[3][1]), fmaxf(s[3][2], s[3][3]));
    float pm = fmaxf(fmaxf(t0, t1), fmaxf(t2, t3));
    pm = fmaxf(pm, __shfl_xor(pm, 16));
    pm = fmaxf(pm, __shfl_xor(pm, 32));
    if (__any(pm > m)) {  // deferred rescale
      const float mn = fmaxf(m, pm);
      const float al = exp2f(SCL * (m - mn));
      m = mn;
#pragma unroll
      for (int reg = 0; reg < 4; ++reg) la[reg] *= al;
#pragma unroll
      for (int nt = 0; nt < 4; ++nt)
#pragma unroll
        for (int reg = 0; reg < 4; ++reg) oacc[nt][reg] *= al;
    }
    const float msc = SCL * m;
    unsigned short* prow = Pl + lr * 68;
#pragma unroll
    for (int nt = 0; nt < 4; ++nt) {
      const float p0 = exp2f(s[nt][0] * SCL - msc);
      const float p1 = exp2f(s[nt][1] * SCL - msc);
      const float p2 = exp2f(s[nt][2] * SCL - msc);
      const float p3 = exp2f(s[nt][3] * SCL - msc);
      const unsigned w01 = cvt_pk_bf16(p0, p1);
      const unsigned w23 = cvt_pk_bf16(p2, p3);
      ushort4 pk;
      pk.x = (unsigned short)w01; pk.y = (unsigned short)(w01 >> 16);
      pk.z = (unsigned short)w23; pk.w = (unsigned short)(w23 >> 16);
      *(ushort4*)(prow + nt * 16 + lg * 4) = pk;
    }
  };

  bf16x8 kbufA[4][2], kbufB[4][2];
  loadK(kbufA, 0);
  issueV(0, 0);

  auto iter = [&](int t, bf16x8 (&kc)[4][2], bf16x8 (&kn)[4][2]) {
    const bool more = (t + 1 < Tb);
    const bool actA = (t < Ta);
    if (more) { loadK(kn, t + 1); issueV((t + 1) & 1, t + 1); }

    // ---- S = K·Q^T (swapped): lane holds S[k][q=lr] ----
    f32x4 sB[4], sA[4];
    __builtin_amdgcn_s_setprio(1);
#pragma unroll
    for (int nt = 0; nt < 4; ++nt) {
      f32x4 z = {0.f, 0.f, 0.f, 0.f};
      z = __builtin_amdgcn_mfma_f32_16x16x32_bf16(kc[nt][0], qfB[0], z, 0, 0, 0);
      sB[nt] = __builtin_amdgcn_mfma_f32_16x16x32_bf16(kc[nt][1], qfB[1], z, 0, 0, 0);
    }
    if (actA)
#pragma unroll
      for (int nt = 0; nt < 4; ++nt) {
        f32x4 z = {0.f, 0.f, 0.f, 0.f};
        z = __builtin_amdgcn_mfma_f32_16x16x32_bf16(kc[nt][0], qfA[0], z, 0, 0, 0);
        sA[nt] = __builtin_amdgcn_mfma_f32_16x16x32_bf16(kc[nt][1], qfA[1], z, 0, 0, 0);
      }
    __builtin_amdgcn_s_setprio(0);

    // ---- softmax B -> paB, then A reuses the same P buffer (in-order DS) ----
    soft(sB, mB, lBa, oB, qrowB, t == Tb - 1, t);
    bf16x8 paB[2], paA[2];
#pragma unroll
    for (int ks = 0; ks < 2; ++ks)
      paB[ks] = *(const bf16x8*)(Pl + lr * 68 + ks * 32 + lg * 8);
    if (actA) {
      soft(sA, mA, lAa, oA, qrowA, t == Ta - 1, t);
#pragma unroll
      for (int ks = 0; ks < 2; ++ks)
        paA[ks] = *(const bf16x8*)(Pl + lr * 68 + ks * 32 + lg * 8);
    }

    // ---- wait this tile's V DMA (counted: K(t+1)+V(t+1)=16 stay in flight) ----
    if (more) asm volatile("s_waitcnt vmcnt(16)" ::: "memory");
    else      asm volatile("s_waitcnt vmcnt(0)" ::: "memory");

    // ---- l += ones·P ; O^T += V^T·P (V frags shared across strips) ----
    const unsigned short* Vw = &Vs[t & 1][0];
    __builtin_amdgcn_s_setprio(1);
    lBa = __builtin_amdgcn_mfma_f32_16x16x32_bf16(onesf, paB[0], lBa, 0, 0, 0);
    lBa = __builtin_amdgcn_mfma_f32_16x16x32_bf16(onesf, paB[1], lBa, 0, 0, 0);
    if (actA) {
      lAa = __builtin_amdgcn_mfma_f32_16x16x32_bf16(onesf, paA[0], lAa, 0, 0, 0);
      lAa = __builtin_amdgcn_mfma_f32_16x16x32_bf16(onesf, paA[1], lAa, 0, 0, 0);
    }
#pragma unroll
    for (int nt = 0; nt < 4; ++nt) {
      const int row = nt * 16 + lr;
      const bf16x8 vb0 = *(const bf16x8*)(Vw + row * 64 + ((lg ^ (row & 7)) * 8));
      const bf16x8 vb1 = *(const bf16x8*)(Vw + row * 64 + (((lg + 4) ^ (row & 7)) * 8));
      oB[nt] = __builtin_amdgcn_mfma_f32_16x16x32_bf16(vb0, paB[0], oB[nt], 0, 0, 0);
      oB[nt] = __builtin_amdgcn_mfma_f32_16x16x32_bf16(vb1, paB[1], oB[nt], 0, 0, 0);
      if (actA) {
        oA[nt] = __builtin_amdgcn_mfma_f32_16x16x32_bf16(vb0, paA[0], oA[nt], 0, 0, 0);
        oA[nt] = __builtin_amdgcn_mfma_f32_16x16x32_bf16(vb1, paA[1], oA[nt], 0, 0, 0);
      }
    }
    __builtin_amdgcn_s_setprio(0);
  };

  int t = 0;
  for (;;) {
    iter(t, kbufA, kbufB); ++t; if (t >= Tb) break;
    iter(t, kbufB, kbufA); ++t; if (t >= Tb) break;
  }

  // ---- normalize + write O^T as bf16 [B][S][H*64]: 4 packed 8B stores/strip ----
  const int b = bh >> 4, h = bh & 15;
  auto wrO = [&](f32x4 (&oacc)[4], float l, int qrow) {
    const float inv = 1.0f / l;
    unsigned short* dst = &O[((size_t)b * 2048 + qrow + lr) * 1024 + h * 64];
#pragma unroll
    for (int nt = 0; nt < 4; ++nt) {
      const unsigned w01 = cvt_pk_bf16(oacc[nt][0] * inv, oacc[nt][1] * inv);
      const unsigned w23 = cvt_pk_bf16(oacc[nt][2] * inv, oacc[nt][3] * inv);
      ushort4 pk;
      pk.x = (unsigned short)w01; pk.y = (unsigned short)(w01 >> 16);
      pk.z = (unsigned short)w23; pk.w = (unsigned short)(w23 >> 16);
      *(ushort4*)(dst + nt * 16 + lg * 4) = pk;
    }
  };
  wrO(oA, lAa[0], qrowA);
  wrO(oB, lBa[0], qrowB);
}

// ---------- stage 3: output projection (BM=64 tiles, 2 blocks/CU), f32 out ----------
__global__ __launch_bounds__(256) void k_out(const unsigned short* __restrict__ Ab,
                                             const unsigned short* __restrict__ Wo,
                                             float* __restrict__ Out) {
  __shared__ __align__(16) unsigned short As[3 * 64 * 32];
  __shared__ __align__(16) unsigned short Bs[3 * 128 * 32];
  const int tid = threadIdx.x;
  const int bm = blockIdx.x * 64, bn = blockIdx.y * 128;
  f32x4 acc[2][4] = {};
  gemm_core_bm64(Ab + (size_t)bm * 1024, Wo + (size_t)bn * 1024, As, Bs, acc, tid);
  const int lane = tid & 63, w = tid >> 6;
  const int wm = (w >> 1) * 32, wn = (w & 1) * 64;
  const int lr = lane & 15, lg = lane >> 4;
#pragma unroll
  for (int mi = 0; mi < 2; ++mi)
#pragma unroll
    for (int ni = 0; ni < 4; ++ni)
#pragma unroll
      for (int reg = 0; reg < 4; ++reg) {
        const int r = bm + wm + mi * 16 + lg * 4 + reg;
        const int e = bn + wn + ni * 16 + lr;
        Out[(size_t)r * 1024 + e] = acc[mi][ni][reg];
      }
}

// ---------- launch ----------
extern "C" void kernel_launch(void* const* d_in, const int* in_sizes, int n_in,
                              void* d_out, int out_size, void* d_ws, size_t ws_size,
                              hipStream_t stream) {
  const float* x = (const float*)d_in[0];
  const float* Wq = (const float*)d_in[1];
  const float* Wk = (const float*)d_in[2];
  const float* Wv = (const float*)d_in[3];
  const float* Wo = (const float*)d_in[4];
  const int* tpos = (const int*)d_in[5];
  float* out = (float*)d_out;
  char* ws = (char*)d_ws;
  const size_t MB = 1024 * 1024;
  unsigned short* xb = (unsigned short*)(ws);             // 8 MB
  unsigned short* wqb = (unsigned short*)(ws + 8 * MB);   // 2 MB
  unsigned short* wkb = (unsigned short*)(ws + 10 * MB);
  unsigned short* wvb = (unsigned short*)(ws + 12 * MB);
  unsigned short* wob = (unsigned short*)(ws + 14 * MB);
  unsigned short* Qb = (unsigned short*)(ws + 16 * MB);   // 8 MB each
  unsigned short* Kb = (unsigned short*)(ws + 24 * MB);
  unsigned short* Vtb = (unsigned short*)(ws + 32 * MB);  // transposed V
  unsigned short* Ab = (unsigned short*)(ws + 40 * MB);
  float* ctab = (float*)(ws + 48 * MB);                   // 256 KB
  float* stab = (float*)(ws + 48 * MB + 256 * 1024);

  k_convert<<<dim3(8192), dim3(256), 0, stream>>>(x, Wq, Wk, Wv, Wo, xb, wqb, wkb,
                                                  wvb, wob);
  k_rope_tab<<<dim3(256), dim3(256), 0, stream>>>(tpos, ctab, stab);
  k_proj<<<dim3(32, 8, 3), dim3(256), 0, stream>>>(xb, wqb, wkb, wvb, ctab, stab,
                                                   Qb, Kb, Vtb);
  k_attn<<<dim3(2048), dim3(64), 0, stream>>>(Qb, Kb, Vtb, Ab);
  k_out<<<dim3(64, 8), dim3(256), 0, stream>>>(Ab, wob, out);
}